// Round 2
// baseline (5359.690 us; speedup 1.0000x reference)
//
#include <hip/hip_runtime.h>
#include <hip/hip_bf16.h>

// CGCNN conv ×4 on MI355X.
// total[e] = P_self[self_idx[e]] + P_nbr[nbr_idx[e]] + nbr_fea[e]@W_nf + b,
// P = x @ [W_self | W_nbr] per node (N=50k), only K=41 GEMM per edge (E=800k).
// Pass1: compute total, BN1 stats, store total as bf16 (if ws allows).
// Pass2: load total bf16, apply BN1 + sigmoid*softplus, atomic segment-sum.
// ws layout (floats): x[N*64] | P[N*256] | summed[N*64] | stats[768] | T_bf16[E*128]
// stats: sum1[128] ssq1[128] scale1[128] shift1[128] sum2[64] ssq2[64] scale2[64] shift2[64]

__device__ __forceinline__ float softplus_f(float x) {
  return fmaxf(x, 0.f) + log1pf(__expf(-fabsf(x)));
}
__device__ __forceinline__ float sigmoid_f(float x) {
  return 1.f / (1.f + __expf(-x));
}
__device__ __forceinline__ int rfl(int v) { return __builtin_amdgcn_readfirstlane(v); }

// x[n][j] = sum_k atom[n][k]*W[k][j] + b[j]; one wave per node; atom row via scalar loads
__global__ __launch_bounds__(256, 3)
void embed_k(const float* __restrict__ atom, const float* __restrict__ W,
             const float* __restrict__ b, float* __restrict__ x, int N) {
  const int lane = threadIdx.x & 63;
  const long nw = (long)gridDim.x * 4;
  float w[92];
#pragma unroll
  for (int k = 0; k < 92; ++k) w[k] = W[k * 64 + lane];
  const float bias = b[lane];
  for (long n = (long)blockIdx.x * 4 + (threadIdx.x >> 6); n < N; n += nw) {
    const int ns = rfl((int)n);
    const float* __restrict__ ar = atom + (long)ns * 92;
    float a0 = bias, a1 = 0.f;
#pragma unroll
    for (int k = 0; k < 92; k += 2) {
      a0 = fmaf(ar[k], w[k], a0);
      a1 = fmaf(ar[k + 1], w[k + 1], a1);
    }
    x[(long)ns * 64 + lane] = a0 + a1;
  }
}

// P[n][0:128] = x[n] @ fcW[0:64][:]; P[n][128:256] = x[n] @ fcW[64:128][:]
// one wave per (node, half); lane owns cols (2*lane, 2*lane+1); x row via scalar loads
__global__ __launch_bounds__(256, 3)
void p_k(const float* __restrict__ x, const float* __restrict__ fcW,
         float* __restrict__ P, int N) {
  const int lane = threadIdx.x & 63;
  const long nw = (long)gridDim.x * 4;
  const long wid = (long)blockIdx.x * 4 + (threadIdx.x >> 6);
  const int half = (int)(wid & 1);
  float2 wp[64];
  const float2* W2 = (const float2*)fcW;
#pragma unroll
  for (int k = 0; k < 64; ++k) wp[k] = W2[(half * 64 + k) * 64 + lane];
  for (long t = wid; t < 2L * N; t += nw) {
    const int ns = rfl((int)(t >> 1));
    const float* __restrict__ xr = x + (long)ns * 64;
    float ax = 0.f, ay = 0.f, bx2 = 0.f, by2 = 0.f;
#pragma unroll
    for (int k = 0; k < 64; k += 2) {
      const float s0 = xr[k], s1 = xr[k + 1];
      ax = fmaf(s0, wp[k].x, ax);
      ay = fmaf(s0, wp[k].y, ay);
      bx2 = fmaf(s1, wp[k + 1].x, bx2);
      by2 = fmaf(s1, wp[k + 1].y, by2);
    }
    ((float2*)P)[(long)ns * 128 + half * 64 + lane] = make_float2(ax + bx2, ay + by2);
  }
}

// MODE 1: compute total, accumulate BN1 stats, optionally store bf16 total.
// MODE 2: recompute total, apply BN1 + activation, atomic segment-sum (fallback).
// One wave per edge; lane owns cols lane (filt) and lane+64 (core).
template <int MODE, bool STORE>
__global__ __launch_bounds__(256, 3)
void edge_main(const float* __restrict__ P, const float* __restrict__ nbr_fea,
               const int* __restrict__ self_idx, const int* __restrict__ nbr_idx,
               const float* __restrict__ fcW, const float* __restrict__ fcb,
               float* __restrict__ stats, float* __restrict__ summed,
               __hip_bfloat16* __restrict__ T, int E) {
  const int tid = threadIdx.x;
  const int lane = tid & 63;
  const long nw = (long)gridDim.x * 4;
  long e = (long)blockIdx.x * 4 + (tid >> 6);

  float2 wfc[41];
#pragma unroll
  for (int k = 0; k < 41; ++k)
    wfc[k] = make_float2(fcW[(128 + k) * 128 + lane], fcW[(128 + k) * 128 + 64 + lane]);
  const float bf = fcb[lane], bc = fcb[64 + lane];
  float sc_f = 0.f, sh_f = 0.f, sc_c = 0.f, sh_c = 0.f;
  if (MODE == 2) {
    sc_f = stats[256 + lane];      sh_f = stats[384 + lane];
    sc_c = stats[256 + 64 + lane]; sh_c = stats[384 + 64 + lane];
  }
  float sum_f = 0.f, ssq_f = 0.f, sum_c = 0.f, ssq_c = 0.f;

  // software pipeline: prefetch next edge's scalar row + indices during compute
  int sA = 0, nA = 0;
  float rA[41];
  if (e < E) {
    const int es = rfl((int)e);
    sA = self_idx[es];
    nA = nbr_idx[es];
    const float* __restrict__ rp = nbr_fea + (long)es * 41;
#pragma unroll
    for (int k = 0; k < 41; ++k) rA[k] = rp[k];
  }
  while (e < E) {
    const long e2 = e + nw;
    int sB = 0, nB = 0;
    float rB[41];
    if (e2 < E) {
      const int es2 = rfl((int)e2);
      sB = self_idx[es2];
      nB = nbr_idx[es2];
      const float* __restrict__ rp2 = nbr_fea + (long)es2 * 41;
#pragma unroll
      for (int k = 0; k < 41; ++k) rB[k] = rp2[k];
    }
    const float g0 = P[(long)sA * 256 + lane];
    const float g1 = P[(long)sA * 256 + 64 + lane];
    const float g2 = P[(long)nA * 256 + 128 + lane];
    const float g3 = P[(long)nA * 256 + 192 + lane];
    float af = 0.f, ac = 0.f;
#pragma unroll
    for (int k = 0; k < 41; ++k) {
      af = fmaf(rA[k], wfc[k].x, af);
      ac = fmaf(rA[k], wfc[k].y, ac);
    }
    const float tf = g0 + g2 + bf + af;
    const float tc = g1 + g3 + bc + ac;
    if (MODE == 1) {
      sum_f += tf; ssq_f = fmaf(tf, tf, ssq_f);
      sum_c += tc; ssq_c = fmaf(tc, tc, ssq_c);
      if (STORE) {
        T[e * 128 + lane] = __float2bfloat16(tf);
        T[e * 128 + 64 + lane] = __float2bfloat16(tc);
      }
    } else {
      const float uf = fmaf(tf, sc_f, sh_f);
      const float uc = fmaf(tc, sc_c, sh_c);
      atomicAdd(&summed[(long)sA * 64 + lane], sigmoid_f(uf) * softplus_f(uc));
    }
    e = e2; sA = sB; nA = nB;
#pragma unroll
    for (int k = 0; k < 41; ++k) rA[k] = rB[k];
  }

  if (MODE == 1) {
    __shared__ float4 red[256];
    red[tid] = make_float4(sum_f, ssq_f, sum_c, ssq_c);
    __syncthreads();
    if (tid < 64) {
      const float4 a = red[tid], b2 = red[tid + 64], c = red[tid + 128], d = red[tid + 192];
      atomicAdd(&stats[tid],            a.x + b2.x + c.x + d.x);
      atomicAdd(&stats[128 + tid],      a.y + b2.y + c.y + d.y);
      atomicAdd(&stats[64 + tid],       a.z + b2.z + c.z + d.z);
      atomicAdd(&stats[128 + 64 + tid], a.w + b2.w + c.w + d.w);
    }
  }
}

// Pass2 (stored path): read bf16 total, apply BN1 + activation, atomic segment-sum
__global__ void edge_apply(const __hip_bfloat16* __restrict__ T, const int* __restrict__ self_idx,
                           const float* __restrict__ stats, float* __restrict__ summed, int E) {
  const int tid = threadIdx.x;
  const int lane = tid & 63;
  const long nw = (long)gridDim.x * 4;
  const float sc_f = stats[256 + lane],      sh_f = stats[384 + lane];
  const float sc_c = stats[256 + 64 + lane], sh_c = stats[384 + 64 + lane];
  for (long e = (long)blockIdx.x * 4 + (tid >> 6); e < E; e += nw) {
    const int es = rfl((int)e);
    const int s = self_idx[es];
    const float tf = __bfloat162float(T[e * 128 + lane]);
    const float tc = __bfloat162float(T[e * 128 + 64 + lane]);
    const float uf = fmaf(tf, sc_f, sh_f);
    const float uc = fmaf(tc, sc_c, sh_c);
    atomicAdd(&summed[(long)s * 64 + lane], sigmoid_f(uf) * softplus_f(uc));
  }
}

__global__ void fin1_k(float* __restrict__ stats, const float* __restrict__ g,
                       const float* __restrict__ b, int E) {
  const int c = threadIdx.x;  // 0..127
  const float mean = stats[c] / (float)E;
  const float var = stats[128 + c] / (float)E - mean * mean;
  const float sc = g[c] * rsqrtf(var + 1e-5f);
  stats[256 + c] = sc;
  stats[384 + c] = fmaf(-mean, sc, b[c]);
}

__global__ void bn2_stats_k(const float* __restrict__ summed, float* __restrict__ stats, int N) {
  const int tid = threadIdx.x;
  const int j = tid & 63;
  const int r = tid >> 6;
  float s = 0.f, q = 0.f;
  for (long n = (long)blockIdx.x * 4 + r; n < N; n += (long)gridDim.x * 4) {
    const float v = summed[n * 64 + j];
    s += v; q = fmaf(v, v, q);
  }
  __shared__ float2 red[256];
  red[tid] = make_float2(s, q);
  __syncthreads();
  if (tid < 64) {
    const float2 a = red[tid], b2 = red[tid + 64], c = red[tid + 128], d = red[tid + 192];
    atomicAdd(&stats[512 + tid], a.x + b2.x + c.x + d.x);
    atomicAdd(&stats[576 + tid], a.y + b2.y + c.y + d.y);
  }
}

__global__ void fin2_k(float* __restrict__ stats, const float* __restrict__ g,
                       const float* __restrict__ b, int N) {
  const int c = threadIdx.x;  // 0..63
  const float mean = stats[512 + c] / (float)N;
  const float var = stats[576 + c] / (float)N - mean * mean;
  const float sc = g[c] * rsqrtf(var + 1e-5f);
  stats[640 + c] = sc;
  stats[704 + c] = fmaf(-mean, sc, b[c]);
}

__global__ void upd_k(const float* __restrict__ x, const float* __restrict__ summed,
                      const float* __restrict__ stats, float* __restrict__ dst, int total) {
  const int idx = blockIdx.x * 256 + threadIdx.x;
  if (idx >= total) return;
  const int j = idx & 63;
  const float v = x[idx] + fmaf(summed[idx], stats[640 + j], stats[704 + j]);
  dst[idx] = softplus_f(v);
}

extern "C" void kernel_launch(void* const* d_in, const int* in_sizes, int n_in,
                              void* d_out, int out_size, void* d_ws, size_t ws_size,
                              hipStream_t stream) {
  const float* atom_fea = (const float*)d_in[0];
  const float* nbr_fea  = (const float*)d_in[1];
  const int*   self_idx = (const int*)d_in[2];
  const int*   nbr_idx  = (const int*)d_in[3];
  const float* emb_W    = (const float*)d_in[4];
  const float* emb_b    = (const float*)d_in[5];
  const float* fc_W     = (const float*)d_in[6];
  const float* fc_b     = (const float*)d_in[7];
  const float* bn1_g    = (const float*)d_in[8];
  const float* bn1_b    = (const float*)d_in[9];
  const float* bn2_g    = (const float*)d_in[10];
  const float* bn2_b    = (const float*)d_in[11];
  float* out = (float*)d_out;

  const int N = in_sizes[0] / 92;
  const int E = in_sizes[2];

  float* x      = (float*)d_ws;
  float* P      = x + (size_t)N * 64;
  float* summed = P + (size_t)N * 256;
  float* stats  = summed + (size_t)N * 64;
  __hip_bfloat16* T = (__hip_bfloat16*)(stats + 768);

  const size_t need = ((size_t)N * 384 + 768) * 4 + (size_t)E * 128 * 2;
  const bool store = ws_size >= need;

  embed_k<<<256, 256, 0, stream>>>(atom_fea, emb_W, emb_b, x, N);

  for (int i = 0; i < 4; ++i) {
    const float* Wi = fc_W + (size_t)i * 169 * 128;
    const float* bi = fc_b + (size_t)i * 128;
    hipMemsetAsync(summed, 0, ((size_t)N * 64 + 768) * sizeof(float), stream);
    p_k<<<512, 256, 0, stream>>>(x, Wi, P, N);
    if (store)
      edge_main<1, true><<<1024, 256, 0, stream>>>(P, nbr_fea, self_idx, nbr_idx, Wi, bi, stats, summed, T, E);
    else
      edge_main<1, false><<<1024, 256, 0, stream>>>(P, nbr_fea, self_idx, nbr_idx, Wi, bi, stats, summed, T, E);
    fin1_k<<<1, 128, 0, stream>>>(stats, bn1_g + (size_t)i * 128, bn1_b + (size_t)i * 128, E);
    if (store)
      edge_apply<<<1024, 256, 0, stream>>>(T, self_idx, stats, summed, E);
    else
      edge_main<2, false><<<1024, 256, 0, stream>>>(P, nbr_fea, self_idx, nbr_idx, Wi, bi, stats, summed, T, E);
    bn2_stats_k<<<256, 256, 0, stream>>>(summed, stats, N);
    fin2_k<<<1, 64, 0, stream>>>(stats, bn2_g + (size_t)i * 64, bn2_b + (size_t)i * 64, N);
    float* dst = (i == 3) ? out : x;
    upd_k<<<(N * 64 + 255) / 256, 256, 0, stream>>>(x, summed, stats, dst, N * 64);
  }
}

// Round 3
// 2369.541 us; speedup vs baseline: 2.2619x; 2.2619x over previous
//
#include <hip/hip_runtime.h>
#include <hip/hip_bf16.h>

// CGCNN conv ×4 on MI355X — MFMA edition.
// total[e][c] = F[e][c] + Pself[self[e]][c] + Pnbr[nbr[e]][c] + b[c]
//   F = nbr_fea @ W_nf  via mfma_f32_16x16x32_bf16, 16-edge tiles
//   P = x @ [W_self | W_nbr]  via MFMA, stored bf16 pair-interleaved:
//     Pu32[n*128 + half*64 + j] packs (col j, col j+64) of that half.
// Pass1 (MODE 1): stats (sum/ssq per col, in-register). Pass2 (MODE 2):
// recompute total, BN1 + sigmoid*softplus, atomic segment-sum.
// Fragment layouts (guide §3, m89-verified):
//   A: row=lane&15, k=(lane>>4)*8+j ;  B: col=lane&15, k=(lane>>4)*8+j
//   D: col=lane&15, row=(lane>>4)*4+reg
// ws (floats): x[N*64] | P(ushort N*256 -> N*128) | summed[N*64] | stats[768]
//              | xb(ushort N*64 -> N*32) | nbrT(ushort E*128 -> E*64)
//              | WBe(16384) | WBp(32768)

typedef __attribute__((ext_vector_type(8))) short short8;
typedef __attribute__((ext_vector_type(4))) float f32x4;

__device__ __forceinline__ float softplus_f(float x) {
  return fmaxf(x, 0.f) + log1pf(__expf(-fabsf(x)));
}
__device__ __forceinline__ float sigmoid_f(float x) {
  return 1.f / (1.f + __expf(-x));
}
__device__ __forceinline__ ushort f2b(float f) {
  __hip_bfloat16 h = __float2bfloat16(f);
  return *reinterpret_cast<ushort*>(&h);
}
__device__ __forceinline__ float b2f(ushort u) {
  return __uint_as_float(((unsigned)u) << 16);
}

// ---- one-time: fc_W -> B-fragment layouts (all 4 layers) ----
// WBe[layer][cb<8][s<2][lane][8] : edge GEMM B (rows 128+k, k zero-padded to 64)
// WBp[layer][cb<16][s<2][lane][8]: P GEMM B (K=64; col<128 -> Wself, else Wnbr)
__global__ void wconv_k(const float* __restrict__ fcW, ushort* __restrict__ WBe,
                        ushort* __restrict__ WBp) {
  const int tid = blockIdx.x * 256 + threadIdx.x;  // 4*48*64 = 12288 threads
  if (tid >= 12288) return;
  const int layer = tid / 3072;
  const int rem = tid % 3072;
  const int unit = rem / 64;
  const int lane = rem % 64;
  const int c16 = lane & 15, r4 = lane >> 4;
  const float* W = fcW + (size_t)layer * 169 * 128;
  if (unit < 16) {
    const int cb = unit >> 1, s = unit & 1;
    ushort* dst = WBe + (((size_t)(layer * 8 + cb) * 2 + s) * 64 + lane) * 8;
#pragma unroll
    for (int j = 0; j < 8; ++j) {
      const int k = s * 32 + r4 * 8 + j;
      dst[j] = f2b(k < 41 ? W[(128 + k) * 128 + cb * 16 + c16] : 0.f);
    }
  } else {
    const int pu = unit - 16;
    const int cb = pu >> 1, s = pu & 1;
    const int c256 = cb * 16 + c16;
    ushort* dst = WBp + (((size_t)(layer * 16 + cb) * 2 + s) * 64 + lane) * 8;
#pragma unroll
    for (int j = 0; j < 8; ++j) {
      const int k = s * 32 + r4 * 8 + j;
      const int row = (c256 < 128) ? k : 64 + k;
      dst[j] = f2b(W[row * 128 + (c256 & 127)]);
    }
  }
}

// ---- one-time: nbr_fea -> bf16 A-fragment tiles [t][s][lane][8] ----
__global__ void nbrconv_k(const float* __restrict__ nbr, ushort* __restrict__ nbrT,
                          int ntiles, int E) {
  const long tid = (long)blockIdx.x * 256 + threadIdx.x;  // ntiles*128
  if (tid >= (long)ntiles * 128) return;
  const long t = tid >> 7;
  const int rem = (int)(tid & 127);
  const int s = rem >> 6, lane = rem & 63;
  const int c16 = lane & 15, r4 = lane >> 4;
  long e = t * 16 + c16;
  if (e >= E) e = E - 1;
  ushort* dst = nbrT + ((t * 2 + s) * 64 + lane) * 8;
#pragma unroll
  for (int j = 0; j < 8; ++j) {
    const int k = s * 32 + r4 * 8 + j;
    dst[j] = f2b(k < 41 ? nbr[e * 41 + k] : 0.f);
  }
}

// ---- embed: x[n][j] = atom[n] @ embW + b ; writes f32 x and bf16 xb ----
__global__ __launch_bounds__(256, 3)
void embed_k(const float* __restrict__ atom, const float* __restrict__ W,
             const float* __restrict__ b, float* __restrict__ x,
             ushort* __restrict__ xb, int N) {
  const int lane = threadIdx.x & 63;
  const long nw = (long)gridDim.x * 4;
  float w[92];
#pragma unroll
  for (int k = 0; k < 92; ++k) w[k] = W[k * 64 + lane];
  const float bias = b[lane];
  for (long n = (long)blockIdx.x * 4 + (threadIdx.x >> 6); n < N; n += nw) {
    const float* __restrict__ ar = atom + n * 92;
    float a0 = bias, a1 = 0.f;
#pragma unroll
    for (int k = 0; k < 92; k += 2) {
      a0 = fmaf(ar[k], w[k], a0);
      a1 = fmaf(ar[k + 1], w[k + 1], a1);
    }
    const float v = a0 + a1;
    x[n * 64 + lane] = v;
    xb[n * 64 + lane] = f2b(v);
  }
}

// ---- P = xb @ WBp (MFMA); one wave per (node-tile, half); pair-packed store ----
__global__ __launch_bounds__(256, 2)
void p_k(const ushort* __restrict__ xb, const ushort* __restrict__ WBp,
         unsigned* __restrict__ Pu, int ntilesN) {
  const int lane = threadIdx.x & 63;
  const int c16 = lane & 15, r4 = lane >> 4;
  const long nw = (long)gridDim.x * 4;
  const f32x4 vz = {0.f, 0.f, 0.f, 0.f};
  for (long u = (long)blockIdx.x * 4 + (threadIdx.x >> 6); u < 2L * ntilesN; u += nw) {
    const long t = u >> 1;
    const int h = (int)(u & 1);
    short8 a[2];
#pragma unroll
    for (int s = 0; s < 2; ++s)
      a[s] = *reinterpret_cast<const short8*>(xb + (t * 16 + c16) * 64 + s * 32 + r4 * 8);
    f32x4 acc[8];
#pragma unroll
    for (int cb = 0; cb < 8; ++cb) {
      acc[cb] = vz;
#pragma unroll
      for (int s = 0; s < 2; ++s) {
        const short8 bfr = *reinterpret_cast<const short8*>(
            WBp + (((size_t)(h * 8 + cb) * 2 + s) * 64 + lane) * 8);
        acc[cb] = __builtin_amdgcn_mfma_f32_16x16x32_bf16(a[s], bfr, acc[cb], 0, 0, 0);
      }
    }
    // pair (cbl, cbl+4): cols j and j+64 of this half -> one dword
#pragma unroll
    for (int jb = 0; jb < 4; ++jb)
#pragma unroll
      for (int r = 0; r < 4; ++r) {
        const long node = t * 16 + r4 * 4 + r;
        const unsigned lo = f2b(acc[jb][r]);
        const unsigned hi = f2b(acc[jb + 4][r]);
        Pu[node * 128 + h * 64 + jb * 16 + c16] = lo | (hi << 16);
      }
  }
}

// ---- edge pass (MFMA). MODE 1: BN1 stats. MODE 2: apply + segment-sum. ----
template <int MODE>
__global__ __launch_bounds__(256, 2)
void edge_k(const ushort* __restrict__ nbrT, const ushort* __restrict__ WBe,
            const ushort* __restrict__ P, const int* __restrict__ self_idx,
            const int* __restrict__ nbr_idx, const float* __restrict__ fcb,
            float* __restrict__ stats, float* __restrict__ summed, int ntiles) {
  const int lane = threadIdx.x & 63;
  const int c16 = lane & 15, r4 = lane >> 4;
  const long nw = (long)gridDim.x * 4;
  const f32x4 vz = {0.f, 0.f, 0.f, 0.f};

  short8 wb[8][2];
#pragma unroll
  for (int cb = 0; cb < 8; ++cb)
#pragma unroll
    for (int s = 0; s < 2; ++s)
      wb[cb][s] = *reinterpret_cast<const short8*>(WBe + (((size_t)cb * 2 + s) * 64 + lane) * 8);

  float bias[8];
#pragma unroll
  for (int cb = 0; cb < 8; ++cb) bias[cb] = fcb[cb * 16 + c16];
  float sc[8], sh[8];
  if (MODE == 2) {
#pragma unroll
    for (int cb = 0; cb < 8; ++cb) {
      sc[cb] = stats[256 + cb * 16 + c16];
      sh[cb] = stats[384 + cb * 16 + c16];
    }
  }
  float sum[8], ssq[8];
#pragma unroll
  for (int cb = 0; cb < 8; ++cb) { sum[cb] = 0.f; ssq[cb] = 0.f; }

  for (long t = (long)blockIdx.x * 4 + (threadIdx.x >> 6); t < ntiles; t += nw) {
    const short8 a0 = *reinterpret_cast<const short8*>(nbrT + (t * 2) * 512 + lane * 8);
    const short8 a1 = *reinterpret_cast<const short8*>(nbrT + (t * 2 + 1) * 512 + lane * 8);
    int se[4], ne[4];
#pragma unroll
    for (int r = 0; r < 4; ++r) {
      se[r] = self_idx[t * 16 + r4 * 4 + r];
      ne[r] = nbr_idx[t * 16 + r4 * 4 + r];
    }
    f32x4 acc[8];
#pragma unroll
    for (int cb = 0; cb < 8; ++cb) {
      acc[cb] = vz;
      acc[cb] = __builtin_amdgcn_mfma_f32_16x16x32_bf16(a0, wb[cb][0], acc[cb], 0, 0, 0);
      acc[cb] = __builtin_amdgcn_mfma_f32_16x16x32_bf16(a1, wb[cb][1], acc[cb], 0, 0, 0);
    }
    float tt[8][4];
#pragma unroll
    for (int jb = 0; jb < 4; ++jb)
#pragma unroll
      for (int r = 0; r < 4; ++r) {
        const unsigned ds = *reinterpret_cast<const unsigned*>(
            P + (long)se[r] * 256 + (jb * 16 + c16) * 2);
        const unsigned dn = *reinterpret_cast<const unsigned*>(
            P + (long)ne[r] * 256 + 128 + (jb * 16 + c16) * 2);
        tt[jb][r]     = acc[jb][r]     + b2f((ushort)ds)         + b2f((ushort)dn)         + bias[jb];
        tt[jb + 4][r] = acc[jb + 4][r] + b2f((ushort)(ds >> 16)) + b2f((ushort)(dn >> 16)) + bias[jb + 4];
      }
    if (MODE == 1) {
#pragma unroll
      for (int cb = 0; cb < 8; ++cb)
#pragma unroll
        for (int r = 0; r < 4; ++r) {
          sum[cb] += tt[cb][r];
          ssq[cb] = fmaf(tt[cb][r], tt[cb][r], ssq[cb]);
        }
    } else {
#pragma unroll
      for (int jb = 0; jb < 4; ++jb)
#pragma unroll
        for (int r = 0; r < 4; ++r) {
          const float uf = fmaf(tt[jb][r], sc[jb], sh[jb]);
          const float uc = fmaf(tt[jb + 4][r], sc[jb + 4], sh[jb + 4]);
          atomicAdd(&summed[(long)se[r] * 64 + jb * 16 + c16],
                    sigmoid_f(uf) * softplus_f(uc));
        }
    }
  }

  if (MODE == 1) {
#pragma unroll
    for (int cb = 0; cb < 8; ++cb) {
      float s = sum[cb], q = ssq[cb];
      s += __shfl_xor(s, 16); q += __shfl_xor(q, 16);
      s += __shfl_xor(s, 32); q += __shfl_xor(q, 32);
      if (lane < 16) {
        atomicAdd(&stats[cb * 16 + lane], s);
        atomicAdd(&stats[128 + cb * 16 + lane], q);
      }
    }
  }
}

__global__ void fin1_k(float* __restrict__ stats, const float* __restrict__ g,
                       const float* __restrict__ b, int E) {
  const int c = threadIdx.x;  // 0..127
  const float mean = stats[c] / (float)E;
  const float var = stats[128 + c] / (float)E - mean * mean;
  const float sc = g[c] * rsqrtf(var + 1e-5f);
  stats[256 + c] = sc;
  stats[384 + c] = fmaf(-mean, sc, b[c]);
}

__global__ void bn2_stats_k(const float* __restrict__ summed, float* __restrict__ stats, int N) {
  const int tid = threadIdx.x;
  const int j = tid & 63;
  const int r = tid >> 6;
  float s = 0.f, q = 0.f;
  for (long n = (long)blockIdx.x * 4 + r; n < N; n += (long)gridDim.x * 4) {
    const float v = summed[n * 64 + j];
    s += v; q = fmaf(v, v, q);
  }
  __shared__ float2 red[256];
  red[tid] = make_float2(s, q);
  __syncthreads();
  if (tid < 64) {
    const float2 a = red[tid], b2 = red[tid + 64], c = red[tid + 128], d = red[tid + 192];
    atomicAdd(&stats[512 + tid], a.x + b2.x + c.x + d.x);
    atomicAdd(&stats[576 + tid], a.y + b2.y + c.y + d.y);
  }
}

__global__ void fin2_k(float* __restrict__ stats, const float* __restrict__ g,
                       const float* __restrict__ b, int N) {
  const int c = threadIdx.x;  // 0..63
  const float mean = stats[512 + c] / (float)N;
  const float var = stats[576 + c] / (float)N - mean * mean;
  const float sc = g[c] * rsqrtf(var + 1e-5f);
  stats[640 + c] = sc;
  stats[704 + c] = fmaf(-mean, sc, b[c]);
}

__global__ void upd_k(const float* __restrict__ x, const float* __restrict__ summed,
                      const float* __restrict__ stats, float* __restrict__ dst,
                      ushort* __restrict__ xb, int total) {
  const int idx = blockIdx.x * 256 + threadIdx.x;
  if (idx >= total) return;
  const int j = idx & 63;
  const float v = softplus_f(x[idx] + fmaf(summed[idx], stats[640 + j], stats[704 + j]));
  dst[idx] = v;
  xb[idx] = f2b(v);
}

extern "C" void kernel_launch(void* const* d_in, const int* in_sizes, int n_in,
                              void* d_out, int out_size, void* d_ws, size_t ws_size,
                              hipStream_t stream) {
  const float* atom_fea = (const float*)d_in[0];
  const float* nbr_fea  = (const float*)d_in[1];
  const int*   self_idx = (const int*)d_in[2];
  const int*   nbr_idx  = (const int*)d_in[3];
  const float* emb_W    = (const float*)d_in[4];
  const float* emb_b    = (const float*)d_in[5];
  const float* fc_W     = (const float*)d_in[6];
  const float* fc_b     = (const float*)d_in[7];
  const float* bn1_g    = (const float*)d_in[8];
  const float* bn1_b    = (const float*)d_in[9];
  const float* bn2_g    = (const float*)d_in[10];
  const float* bn2_b    = (const float*)d_in[11];
  float* out = (float*)d_out;

  const int N = in_sizes[0] / 92;
  const int E = in_sizes[2];
  const int ntilesE = (E + 15) / 16;
  const int ntilesN = (N + 15) / 16;

  float* x      = (float*)d_ws;
  ushort* P     = (ushort*)(x + (size_t)N * 64);          // N*256 ushorts
  float* summed = (float*)(P + (size_t)N * 256);
  float* stats  = summed + (size_t)N * 64;
  ushort* xb    = (ushort*)(stats + 768);                 // N*64 ushorts
  ushort* nbrT  = xb + (size_t)N * 64;                    // ntilesE*1024 ushorts
  ushort* WBe   = nbrT + (size_t)ntilesE * 1024;          // 32768 ushorts
  ushort* WBp   = WBe + 32768;                            // 65536 ushorts

  wconv_k<<<48, 256, 0, stream>>>(fc_W, WBe, WBp);
  nbrconv_k<<<(ntilesE * 128 + 255) / 256, 256, 0, stream>>>(nbr_fea, nbrT, ntilesE, E);
  embed_k<<<1024, 256, 0, stream>>>(atom_fea, emb_W, emb_b, x, xb, N);

  for (int i = 0; i < 4; ++i) {
    const ushort* WBei = WBe + (size_t)i * 8192;
    const ushort* WBpi = WBp + (size_t)i * 16384;
    const float* bi = fc_b + (size_t)i * 128;
    hipMemsetAsync(summed, 0, ((size_t)N * 64 + 768) * sizeof(float), stream);
    p_k<<<1024, 256, 0, stream>>>(xb, WBpi, (unsigned*)P, ntilesN);
    edge_k<1><<<2048, 256, 0, stream>>>(nbrT, WBei, P, self_idx, nbr_idx, bi, stats, summed, ntilesE);
    fin1_k<<<1, 128, 0, stream>>>(stats, bn1_g + (size_t)i * 128, bn1_b + (size_t)i * 128, E);
    edge_k<2><<<2048, 256, 0, stream>>>(nbrT, WBei, P, self_idx, nbr_idx, bi, stats, summed, ntilesE);
    bn2_stats_k<<<256, 256, 0, stream>>>(summed, stats, N);
    fin2_k<<<1, 64, 0, stream>>>(stats, bn2_g + (size_t)i * 64, bn2_b + (size_t)i * 64, N);
    float* dst = (i == 3) ? out : x;
    upd_k<<<(N * 64 + 255) / 256, 256, 0, stream>>>(x, summed, stats, dst, xb, N * 64);
  }
}